// Round 1
// baseline (925.172 us; speedup 1.0000x reference)
//
#include <hip/hip_runtime.h>
#include <hip/hip_bf16.h>

#define THREADS 256

// ---------------- graph preprocessing ----------------

__global__ __launch_bounds__(256) void init_cnt_kernel(int* cnt, int n) {
    int i = blockIdx.x * blockDim.x + threadIdx.x;
    if (i < n) cnt[i] = 1;   // self loop
}

__global__ __launch_bounds__(256) void count_edges_kernel(const int* ei, int* cnt, int E) {
    int e = blockIdx.x * blockDim.x + threadIdx.x;
    if (e < E) atomicAdd(&cnt[ei[E + e]], 1);   // dst row
}

__global__ __launch_bounds__(256) void dinv_kernel(const int* cnt, float* dinv, int n) {
    int i = blockIdx.x * blockDim.x + threadIdx.x;
    if (i < n) dinv[i] = rsqrtf((float)cnt[i]);
}

// single-block exclusive scan of cnt[0..n) -> row_ptr[0..n]
__global__ __launch_bounds__(1024) void scan_kernel(const int* cnt, int* row_ptr, int n) {
    __shared__ int sh[1024];
    __shared__ int carry;
    if (threadIdx.x == 0) carry = 0;
    __syncthreads();
    for (int base = 0; base < n; base += 1024) {
        int i = base + (int)threadIdx.x;
        int v = (i < n) ? cnt[i] : 0;
        sh[threadIdx.x] = v;
        __syncthreads();
        for (int off = 1; off < 1024; off <<= 1) {
            int t = (threadIdx.x >= (unsigned)off) ? sh[threadIdx.x - off] : 0;
            __syncthreads();
            sh[threadIdx.x] += t;
            __syncthreads();
        }
        int incl = sh[threadIdx.x];
        int excl = incl - v;
        if (i < n) row_ptr[i] = carry + excl;
        __syncthreads();
        if (threadIdx.x == 0) carry += sh[1023];
        __syncthreads();
    }
    if (threadIdx.x == 0) row_ptr[n] = carry;
}

__global__ __launch_bounds__(256) void init_cursor_kernel(const int* row_ptr, int* cursor, int n) {
    int i = blockIdx.x * blockDim.x + threadIdx.x;
    if (i < n) cursor[i] = row_ptr[i];
}

__global__ __launch_bounds__(256) void fill_self_kernel(int* cursor, int* src_sorted, int n) {
    int i = blockIdx.x * blockDim.x + threadIdx.x;
    if (i < n) {
        int pos = atomicAdd(&cursor[i], 1);
        src_sorted[pos] = i;
    }
}

__global__ __launch_bounds__(256) void fill_edges_kernel(const int* ei, int* cursor, int* src_sorted, int E) {
    int e = blockIdx.x * blockDim.x + threadIdx.x;
    if (e < E) {
        int s = ei[e];
        int d = ei[E + e];
        int pos = atomicAdd(&cursor[d], 1);
        src_sorted[pos] = s;
    }
}

// ---------------- GEMM: C[M,N] = A[M,K] * B[K,N], f32 ----------------
// BM=64, BN=64, BK=16, 256 threads, 4x4 per thread. N%64==0, K%16==0.
__global__ __launch_bounds__(256) void gemm64_kernel(const float* __restrict__ A,
                                                     const float* __restrict__ B,
                                                     float* __restrict__ C,
                                                     int M, int K, int N) {
    __shared__ float As[16][68];
    __shared__ float Bs[16][68];
    int m0 = blockIdx.x * 64;
    int n0 = blockIdx.y * 64;
    int tid = threadIdx.x;
    int tx = tid & 15;
    int ty = tid >> 4;
    float acc[4][4] = {};
    for (int k0 = 0; k0 < K; k0 += 16) {
#pragma unroll
        for (int i = 0; i < 4; i++) {
            int idx = tid + i * 256;
            int r = idx >> 4, c = idx & 15;
            int mm = m0 + r;
            As[c][r] = (mm < M) ? A[(long)mm * K + k0 + c] : 0.f;
        }
#pragma unroll
        for (int i = 0; i < 4; i++) {
            int idx = tid + i * 256;
            int r = idx >> 6, c = idx & 63;
            Bs[r][c] = B[(long)(k0 + r) * N + n0 + c];
        }
        __syncthreads();
#pragma unroll
        for (int kk = 0; kk < 16; kk++) {
            float a[4], b[4];
#pragma unroll
            for (int i = 0; i < 4; i++) a[i] = As[kk][ty * 4 + i];
#pragma unroll
            for (int j = 0; j < 4; j++) b[j] = Bs[kk][tx * 4 + j];
#pragma unroll
            for (int i = 0; i < 4; i++)
#pragma unroll
                for (int j = 0; j < 4; j++) acc[i][j] += a[i] * b[j];
        }
        __syncthreads();
    }
#pragma unroll
    for (int i = 0; i < 4; i++) {
        int mm = m0 + ty * 4 + i;
        if (mm >= M) continue;
#pragma unroll
        for (int j = 0; j < 4; j++) C[(long)mm * N + n0 + tx * 4 + j] = acc[i][j];
    }
}

// small GEMM: whole W in LDS, 64 rows per block. KK,NN compile-time.
template <int KK, int NN>
__global__ __launch_bounds__(256) void gemm_small_kernel(const float* __restrict__ A,
                                                         const float* __restrict__ B,
                                                         float* __restrict__ C, int M) {
    __shared__ float Ws[KK * NN];
    __shared__ float Xs[64 * KK];
    int m0 = blockIdx.x * 64;
    for (int idx = threadIdx.x; idx < KK * NN; idx += 256) Ws[idx] = B[idx];
    for (int idx = threadIdx.x; idx < 64 * KK; idx += 256) {
        int r = idx / KK, c = idx % KK;
        int mm = m0 + r;
        Xs[idx] = (mm < M) ? A[(long)mm * KK + c] : 0.f;
    }
    __syncthreads();
    const int RG = 256 / NN;       // row groups
    const int RPT = 64 / RG;       // rows per thread
    int col = threadIdx.x % NN;
    int r0 = threadIdx.x / NN;
    float acc[RPT];
#pragma unroll
    for (int j = 0; j < RPT; j++) acc[j] = 0.f;
    for (int k = 0; k < KK; k++) {
        float w = Ws[k * NN + col];
#pragma unroll
        for (int j = 0; j < RPT; j++) acc[j] += Xs[(r0 + j * RG) * KK + k] * w;
    }
#pragma unroll
    for (int j = 0; j < RPT; j++) {
        int mm = m0 + r0 + j * RG;
        if (mm < M) C[(long)mm * NN + col] = acc[j];
    }
}

// ---------------- aggregation: out[i,:] = relu(b + sum_e dinv[s]*dinv[i]*t[s,:]) ----------------
template <int D>
__global__ __launch_bounds__(256) void agg_kernel(const float* __restrict__ t,
                                                  const int* __restrict__ row_ptr,
                                                  const int* __restrict__ src_sorted,
                                                  const float* __restrict__ dinv,
                                                  const float* __restrict__ bias,
                                                  float* __restrict__ out, int n) {
    const int NPB = 256 / D;
    int g = threadIdx.x / D;
    int col = threadIdx.x % D;
    int node = blockIdx.x * NPB + g;
    if (node >= n) return;
    float di = dinv[node];
    int beg = row_ptr[node], end = row_ptr[node + 1];
    float acc = 0.f;
    for (int e = beg; e < end; ++e) {
        int s = src_sorted[e];
        float nrm = di * dinv[s];
        acc += nrm * t[(long)s * D + col];
    }
    acc += bias[col];
    out[(long)node * D + col] = fmaxf(acc, 0.f);
}

// ---------------- decoder: out[k,e] = dot(z[s_e], z[d_e]) for all k ----------------
__global__ __launch_bounds__(256) void decoder_kernel(const float* __restrict__ z,
                                                      const int* __restrict__ ei,
                                                      float* __restrict__ out,
                                                      int E, int K, int ZK) {
    int e = blockIdx.x * blockDim.x + threadIdx.x;
    if (e >= E) return;
    int s = ei[e];
    int d = ei[E + e];
    const float* zs = z + (long)s * ZK;
    const float* zd = z + (long)d * ZK;
    float acc = 0.f;
    for (int k = 0; k < ZK; k++) acc += zs[k] * zd[k];
    for (int k = 0; k < K; k++) out[(long)k * E + e] = acc;
}

// ---------------- launch ----------------

extern "C" void kernel_launch(void* const* d_in, const int* in_sizes, int n_in,
                              void* d_out, int out_size, void* d_ws, size_t ws_size,
                              hipStream_t stream) {
    const float* x  = (const float*)d_in[0];
    const int*   ei = (const int*)d_in[1];
    const float* W1 = (const float*)d_in[3];
    const float* b1 = (const float*)d_in[4];
    const float* W2 = (const float*)d_in[5];
    const float* b2 = (const float*)d_in[6];
    const float* W3 = (const float*)d_in[7];
    const float* b3 = (const float*)d_in[8];
    const float* Wk = (const float*)d_in[9];
    const float* bk = (const float*)d_in[10];
    float* out = (float*)d_out;

    const int D1 = in_sizes[4];            // 256
    const int D2 = in_sizes[6];            // 128
    const int D3 = in_sizes[8];            // 32
    const int ZK = in_sizes[10];           // 8
    const int F  = in_sizes[3] / D1;       // 256
    const int N  = in_sizes[0] / F;        // 50000
    const int E  = in_sizes[1] / 2;        // 800000
    const int K  = out_size / E;           // 8
    const int M  = E + N;                  // edges incl self loops

    // workspace layout
    size_t off = 0;
    auto alloc = [&](size_t bytes) -> void* {
        off = (off + 255) & ~(size_t)255;
        void* p = (char*)d_ws + off;
        off += bytes;
        return p;
    };
    int*   cnt        = (int*)alloc((size_t)N * sizeof(int));
    int*   row_ptr    = (int*)alloc((size_t)(N + 1) * sizeof(int));
    int*   cursor     = (int*)alloc((size_t)N * sizeof(int));
    float* dinv       = (float*)alloc((size_t)N * sizeof(float));
    int*   src_sorted = (int*)alloc((size_t)M * sizeof(int));
    float* bufA       = (float*)alloc((size_t)N * F * sizeof(float));
    float* bufB       = (float*)alloc((size_t)N * F * sizeof(float));
    (void)ws_size; (void)n_in;

    int nbN = (N + THREADS - 1) / THREADS;
    int nbE = (E + THREADS - 1) / THREADS;

    // ---- graph prep ----
    init_cnt_kernel<<<nbN, THREADS, 0, stream>>>(cnt, N);
    count_edges_kernel<<<nbE, THREADS, 0, stream>>>(ei, cnt, E);
    dinv_kernel<<<nbN, THREADS, 0, stream>>>(cnt, dinv, N);
    scan_kernel<<<1, 1024, 0, stream>>>(cnt, row_ptr, N);
    init_cursor_kernel<<<nbN, THREADS, 0, stream>>>(row_ptr, cursor, N);
    fill_self_kernel<<<nbN, THREADS, 0, stream>>>(cursor, src_sorted, N);
    fill_edges_kernel<<<nbE, THREADS, 0, stream>>>(ei, cursor, src_sorted, E);

    int mb = (N + 63) / 64;

    // ---- layer 1: t1 = x@W1 (F->D1); h1 = relu(agg(t1)+b1) ----
    {
        dim3 grid(mb, D1 / 64);
        gemm64_kernel<<<grid, THREADS, 0, stream>>>(x, W1, bufA, N, F, D1);
        agg_kernel<256><<<N, THREADS, 0, stream>>>(bufA, row_ptr, src_sorted, dinv, b1, bufB, N);
    }
    // ---- layer 2: t2 = h1@W2 (D1->D2); h2 = relu(agg(t2)+b2) ----
    {
        dim3 grid(mb, D2 / 64);
        gemm64_kernel<<<grid, THREADS, 0, stream>>>(bufB, W2, bufA, N, D1, D2);
        int blocks = (N * 1 + 1) / 2;  // NPB=2
        agg_kernel<128><<<(N + 1) / 2, THREADS, 0, stream>>>(bufA, row_ptr, src_sorted, dinv, b2, bufB, N);
        (void)blocks;
    }
    // ---- layer 3: t3 = h2@W3 (D2=128 -> D3=32) ----
    {
        gemm_small_kernel<128, 32><<<mb, THREADS, 0, stream>>>(bufB, W3, bufA, N);
        agg_kernel<32><<<(N + 7) / 8, THREADS, 0, stream>>>(bufA, row_ptr, src_sorted, dinv, b3, bufB, N);
    }
    // ---- layer K: tk = h3@Wk (D3=32 -> ZK=8); z = relu(agg(tk)+bk) ----
    {
        gemm_small_kernel<32, 8><<<mb, THREADS, 0, stream>>>(bufB, Wk, bufA, N);
        agg_kernel<8><<<(N + 31) / 32, THREADS, 0, stream>>>(bufA, row_ptr, src_sorted, dinv, bk, bufB, N);
    }
    // ---- decoder: out[k,e] = dot(z[s],z[d]); identical across k ----
    decoder_kernel<<<nbE, THREADS, 0, stream>>>(bufB, ei, out, E, K, ZK);

    (void)D3; (void)ZK;
}

// Round 2
// 569.130 us; speedup vs baseline: 1.6256x; 1.6256x over previous
//
#include <hip/hip_runtime.h>
#include <hip/hip_bf16.h>

#define THREADS 256

typedef __attribute__((ext_vector_type(4))) float f32x4;
typedef __attribute__((ext_vector_type(8))) short short8;
typedef __attribute__((ext_vector_type(4))) unsigned short u16x4;

__device__ inline unsigned short f2bf(float f) {
    unsigned int u = __builtin_bit_cast(unsigned int, f);
    unsigned int r = (u + 0x7FFFu + ((u >> 16) & 1u)) >> 16;
    return (unsigned short)r;
}
__device__ inline float bf2f(unsigned short h) {
    unsigned int u = ((unsigned int)h) << 16;
    return __builtin_bit_cast(float, u);
}

// ---------------- graph preprocessing ----------------

__global__ __launch_bounds__(256) void init_cnt_kernel(int* cnt, int n) {
    int i = blockIdx.x * blockDim.x + threadIdx.x;
    if (i < n) cnt[i] = 1;   // self loop
}

__global__ __launch_bounds__(256) void count_edges_kernel(const int* ei, int* cnt, int E) {
    int e = blockIdx.x * blockDim.x + threadIdx.x;
    if (e < E) atomicAdd(&cnt[ei[E + e]], 1);   // dst row
}

__global__ __launch_bounds__(256) void dinv_kernel(const int* cnt, float* dinv, int n) {
    int i = blockIdx.x * blockDim.x + threadIdx.x;
    if (i < n) dinv[i] = rsqrtf((float)cnt[i]);
}

// single-block exclusive scan: 1024 threads, chunked
__global__ __launch_bounds__(1024) void scan_kernel(const int* cnt, int* row_ptr, int n) {
    __shared__ int sh[1024];
    int chunk = (n + 1023) >> 10;
    int beg = (int)threadIdx.x * chunk;
    int end = min(beg + chunk, n);
    int s = 0;
    for (int i = beg; i < end; ++i) s += cnt[i];
    sh[threadIdx.x] = s;
    __syncthreads();
    for (int off = 1; off < 1024; off <<= 1) {
        int t = (threadIdx.x >= (unsigned)off) ? sh[threadIdx.x - off] : 0;
        __syncthreads();
        sh[threadIdx.x] += t;
        __syncthreads();
    }
    int run = sh[threadIdx.x] - s;   // exclusive prefix
    for (int i = beg; i < end; ++i) { row_ptr[i] = run; run += cnt[i]; }
    if (threadIdx.x == 1023) row_ptr[n] = run;
}

__global__ __launch_bounds__(256) void init_cursor_kernel(const int* row_ptr, int* cursor, int n) {
    int i = blockIdx.x * blockDim.x + threadIdx.x;
    if (i < n) cursor[i] = row_ptr[i];
}

__global__ __launch_bounds__(256) void fill_self_kernel(int* cursor, int* src_sorted, int n) {
    int i = blockIdx.x * blockDim.x + threadIdx.x;
    if (i < n) {
        int pos = atomicAdd(&cursor[i], 1);
        src_sorted[pos] = i;
    }
}

__global__ __launch_bounds__(256) void fill_edges_kernel(const int* ei, int* cursor, int* src_sorted, int E) {
    int e = blockIdx.x * blockDim.x + threadIdx.x;
    if (e < E) {
        int s = ei[e];
        int d = ei[E + e];
        int pos = atomicAdd(&cursor[d], 1);
        src_sorted[pos] = s;
    }
}

// ---------------- split-bf16 conversion ----------------
// A' = [hi(x) | lo(x) | hi(x)]  (row length 3F)
__global__ __launch_bounds__(256) void convert_x_kernel(const float* __restrict__ x,
                                                        unsigned short* __restrict__ xs,
                                                        int n, int F) {
    long idx = (long)blockIdx.x * 256 + threadIdx.x;
    long total = (long)n * (F / 4);
    if (idx >= total) return;
    int row = (int)(idx / (F / 4));
    int c4 = (int)(idx % (F / 4)) * 4;
    f32x4 v = *(const f32x4*)&x[(long)row * F + c4];
    u16x4 hi, lo;
#pragma unroll
    for (int j = 0; j < 4; ++j) {
        hi[j] = f2bf(v[j]);
        lo[j] = f2bf(v[j] - bf2f(hi[j]));
    }
    unsigned short* base = xs + (long)row * 3 * F;
    *(u16x4*)&base[c4] = hi;
    *(u16x4*)&base[F + c4] = lo;
    *(u16x4*)&base[2 * F + c4] = hi;
}

// W [K,N] f32 -> Wt [N, 3K] bf16 transposed: rows of B' = [hi; hi; lo]
__global__ __launch_bounds__(256) void convert_w_kernel(const float* __restrict__ W,
                                                        unsigned short* __restrict__ Wt,
                                                        int K, int N) {
    int idx = blockIdx.x * 256 + threadIdx.x;
    if (idx >= K * N) return;
    int k = idx / N, n = idx % N;
    float v = W[(long)k * N + n];
    unsigned short hi = f2bf(v);
    unsigned short lo = f2bf(v - bf2f(hi));
    unsigned short* base = Wt + (long)n * 3 * K;
    base[k] = hi;
    base[K + k] = hi;
    base[2 * K + k] = lo;
}

// ---------------- MFMA bf16 GEMM: C[M,N] = A[M,Kp] * Bt[N,Kp]^T, epilogue *dinv[row] ----------------
// BM=128, BN=64, BK=64; 256 threads = 4 waves (2m x 2n); 16x16x32 MFMA.
// LDS in fragment-linear chunk order -> conflict-free b128 reads/writes.
__global__ __launch_bounds__(256) void gemm_bf16_kernel(const unsigned short* __restrict__ A,
                                                        const unsigned short* __restrict__ Bt,
                                                        const float* __restrict__ dinv,
                                                        float* __restrict__ C,
                                                        int M, int Kp, int N) {
    __shared__ short As[128 * 64];   // 1024 chunks of 8 bf16
    __shared__ short Bs[64 * 64];    // 512 chunks
    const int tid = threadIdx.x;
    const int m0 = blockIdx.x * 128;
    const int n0 = blockIdx.y * 64;
    const int wave = tid >> 6, l = tid & 63;
    const int wm = wave >> 1, wn = wave & 1;
    const int lr = l & 15, lg = l >> 4;
    f32x4 acc[4][2] = {};
    for (int k0 = 0; k0 < Kp; k0 += 64) {
#pragma unroll
        for (int it = 0; it < 4; ++it) {
            int chunk = it * 256 + tid;
            int mi = chunk >> 7;
            int ks = (chunk >> 6) & 1;
            int cl = chunk & 63;
            long row = m0 + mi * 16 + (cl & 15);
            int gk = k0 + ks * 32 + ((cl >> 4) << 3);
            *(short8*)&As[chunk * 8] = *(const short8*)&A[row * Kp + gk];
        }
#pragma unroll
        for (int it = 0; it < 2; ++it) {
            int chunk = it * 256 + tid;
            int ni = chunk >> 7;
            int ks = (chunk >> 6) & 1;
            int cl = chunk & 63;
            long col = n0 + ni * 16 + (cl & 15);
            int gk = k0 + ks * 32 + ((cl >> 4) << 3);
            *(short8*)&Bs[chunk * 8] = *(const short8*)&Bt[col * Kp + gk];
        }
        __syncthreads();
#pragma unroll
        for (int ks = 0; ks < 2; ++ks) {
            short8 a[4], b[2];
#pragma unroll
            for (int mi = 0; mi < 4; ++mi)
                a[mi] = *(const short8*)&As[(((wm * 4 + mi) * 2 + ks) * 64 + l) * 8];
#pragma unroll
            for (int ni = 0; ni < 2; ++ni)
                b[ni] = *(const short8*)&Bs[(((wn * 2 + ni) * 2 + ks) * 64 + l) * 8];
#pragma unroll
            for (int mi = 0; mi < 4; ++mi)
#pragma unroll
                for (int ni = 0; ni < 2; ++ni)
                    acc[mi][ni] = __builtin_amdgcn_mfma_f32_16x16x32_bf16(a[mi], b[ni], acc[mi][ni], 0, 0, 0);
        }
        __syncthreads();
    }
#pragma unroll
    for (int mi = 0; mi < 4; ++mi) {
        int rbase = m0 + wm * 64 + mi * 16 + lg * 4;
#pragma unroll
        for (int ni = 0; ni < 2; ++ni) {
            int col = n0 + wn * 32 + ni * 16 + lr;
#pragma unroll
            for (int r = 0; r < 4; ++r) {
                int row = rbase + r;
                if (row < M) C[(long)row * N + col] = acc[mi][ni][r] * dinv[row];
            }
        }
    }
}

// ---------------- small f32 GEMM with dinv epilogue ----------------
template <int KK, int NN>
__global__ __launch_bounds__(256) void gemm_small_kernel(const float* __restrict__ A,
                                                         const float* __restrict__ B,
                                                         const float* __restrict__ dinv,
                                                         float* __restrict__ C, int M) {
    __shared__ float Ws[KK * NN];
    __shared__ float Xs[64 * KK];
    int m0 = blockIdx.x * 64;
    for (int idx = threadIdx.x; idx < KK * NN; idx += 256) Ws[idx] = B[idx];
    for (int idx = threadIdx.x; idx < 64 * KK; idx += 256) {
        int r = idx / KK, c = idx % KK;
        int mm = m0 + r;
        Xs[idx] = (mm < M) ? A[(long)mm * KK + c] : 0.f;
    }
    __syncthreads();
    const int RG = 256 / NN;
    const int RPT = 64 / RG;
    int col = threadIdx.x % NN;
    int r0 = threadIdx.x / NN;
    float acc[RPT];
#pragma unroll
    for (int j = 0; j < RPT; j++) acc[j] = 0.f;
    for (int k = 0; k < KK; k++) {
        float w = Ws[k * NN + col];
#pragma unroll
        for (int j = 0; j < RPT; j++) acc[j] += Xs[(r0 + j * RG) * KK + k] * w;
    }
#pragma unroll
    for (int j = 0; j < RPT; j++) {
        int mm = m0 + r0 + j * RG;
        if (mm < M) C[(long)mm * NN + col] = acc[j] * dinv[mm];
    }
}

// ---------------- aggregation (pre-scaled rows): out[i] = relu(dinv[i]*sum ts[s] + b) ----------------
// G = D/4 lanes per node, float4 gathers, 4-edge unroll.
// SPLIT: write bf16 [hi|lo|hi] row (len 3D) for next MFMA GEMM; else f32.
template <int D, bool SPLIT>
__global__ __launch_bounds__(256) void agg4_kernel(const float* __restrict__ ts,
                                                   const int* __restrict__ row_ptr,
                                                   const int* __restrict__ src_sorted,
                                                   const float* __restrict__ dinv,
                                                   const float* __restrict__ bias,
                                                   float* __restrict__ out,
                                                   unsigned short* __restrict__ out_s,
                                                   int n) {
    const int G = D / 4;
    const int NPB = 256 / G;
    int g = threadIdx.x / G;
    int lane = threadIdx.x % G;
    int node = blockIdx.x * NPB + g;
    if (node >= n) return;
    int beg = row_ptr[node], end = row_ptr[node + 1];
    const f32x4* tsv = (const f32x4*)ts;
    f32x4 acc = {0.f, 0.f, 0.f, 0.f};
    int e = beg;
    for (; e + 4 <= end; e += 4) {
        int s0 = src_sorted[e];
        int s1 = src_sorted[e + 1];
        int s2 = src_sorted[e + 2];
        int s3 = src_sorted[e + 3];
        f32x4 v0 = tsv[(long)s0 * G + lane];
        f32x4 v1 = tsv[(long)s1 * G + lane];
        f32x4 v2 = tsv[(long)s2 * G + lane];
        f32x4 v3 = tsv[(long)s3 * G + lane];
        acc += (v0 + v1) + (v2 + v3);
    }
    for (; e < end; ++e) {
        int s = src_sorted[e];
        acc += tsv[(long)s * G + lane];
    }
    float di = dinv[node];
    f32x4 b4 = *(const f32x4*)&bias[lane * 4];
    f32x4 v = acc * di + b4;
#pragma unroll
    for (int j = 0; j < 4; ++j) v[j] = fmaxf(v[j], 0.f);
    if constexpr (SPLIT) {
        u16x4 hi, lo;
#pragma unroll
        for (int j = 0; j < 4; ++j) {
            hi[j] = f2bf(v[j]);
            lo[j] = f2bf(v[j] - bf2f(hi[j]));
        }
        unsigned short* base = out_s + (long)node * 3 * D;
        int c4 = lane * 4;
        *(u16x4*)&base[c4] = hi;
        *(u16x4*)&base[D + c4] = lo;
        *(u16x4*)&base[2 * D + c4] = hi;
    } else {
        *(f32x4*)&out[(long)node * D + lane * 4] = v;
    }
}

// ---------------- decoder: out[k,e] = dot(z[s_e], z[d_e]) (identical across k) ----------------
__global__ __launch_bounds__(256) void decoder_kernel(const float* __restrict__ z,
                                                      const int* __restrict__ ei,
                                                      float* __restrict__ out,
                                                      int E, int K) {
    int e = blockIdx.x * blockDim.x + threadIdx.x;
    if (e >= E) return;
    int s = ei[e];
    int d = ei[E + e];
    const f32x4* zv = (const f32x4*)z;
    f32x4 a0 = zv[(long)s * 2], a1 = zv[(long)s * 2 + 1];
    f32x4 b0 = zv[(long)d * 2], b1 = zv[(long)d * 2 + 1];
    f32x4 p = a0 * b0 + a1 * b1;
    float acc = p[0] + p[1] + p[2] + p[3];
    for (int k = 0; k < K; k++) out[(long)k * E + e] = acc;
}

// ---------------- launch ----------------

extern "C" void kernel_launch(void* const* d_in, const int* in_sizes, int n_in,
                              void* d_out, int out_size, void* d_ws, size_t ws_size,
                              hipStream_t stream) {
    const float* x  = (const float*)d_in[0];
    const int*   ei = (const int*)d_in[1];
    const float* W1 = (const float*)d_in[3];
    const float* b1 = (const float*)d_in[4];
    const float* W2 = (const float*)d_in[5];
    const float* b2 = (const float*)d_in[6];
    const float* W3 = (const float*)d_in[7];
    const float* b3 = (const float*)d_in[8];
    const float* Wk = (const float*)d_in[9];
    const float* bk = (const float*)d_in[10];
    float* out = (float*)d_out;

    const int D1 = in_sizes[4];            // 256
    const int D2 = in_sizes[6];            // 128
    const int F  = in_sizes[3] / D1;       // 256
    const int N  = in_sizes[0] / F;        // 50000
    const int E  = in_sizes[1] / 2;        // 800000
    const int K  = out_size / E;           // 8
    const int M  = E + N;                  // edges incl self loops
    const int Mpad = (N + 127) & ~127;     // 50048

    // workspace layout
    size_t off = 0;
    auto alloc = [&](size_t bytes) -> void* {
        off = (off + 255) & ~(size_t)255;
        void* p = (char*)d_ws + off;
        off += bytes;
        return p;
    };
    int*   cnt        = (int*)alloc((size_t)N * sizeof(int));
    int*   row_ptr    = (int*)alloc((size_t)(N + 1) * sizeof(int));
    int*   cursor     = (int*)alloc((size_t)N * sizeof(int));
    float* dinv       = (float*)alloc((size_t)N * sizeof(float));
    int*   src_sorted = (int*)alloc((size_t)M * sizeof(int));
    unsigned short* xs  = (unsigned short*)alloc((size_t)Mpad * 3 * F * sizeof(short));   // 76.9 MB
    unsigned short* Wt1 = (unsigned short*)alloc((size_t)D1 * 3 * F * sizeof(short));
    unsigned short* Wt2 = (unsigned short*)alloc((size_t)D2 * 3 * D1 * sizeof(short));
    float* bufTS      = (float*)alloc((size_t)Mpad * 256 * sizeof(float));                // 51.2 MB
    (void)ws_size; (void)n_in;

    float* ts1 = bufTS;                       // [Mpad,256]
    unsigned short* h1s = xs;                 // reuse xs after GEMM1  [Mpad,768] bf16
    float* ts2 = bufTS;                       // [Mpad,128]
    float* h2  = bufTS + (size_t)Mpad * 128;  // [Mpad,128]
    float* xsf = (float*)xs;                  // reuse xs region after GEMM2
    float* ts3 = xsf;                         // [Mpad,32]
    float* h3  = xsf + (size_t)Mpad * 32;     // [Mpad,32]
    float* tsk = xsf + (size_t)Mpad * 64;     // [Mpad,8]
    float* z   = xsf + (size_t)Mpad * 72;     // [Mpad,8]

    int nbN = (N + THREADS - 1) / THREADS;
    int nbE = (E + THREADS - 1) / THREADS;

    // ---- graph prep ----
    init_cnt_kernel<<<nbN, THREADS, 0, stream>>>(cnt, N);
    count_edges_kernel<<<nbE, THREADS, 0, stream>>>(ei, cnt, E);
    dinv_kernel<<<nbN, THREADS, 0, stream>>>(cnt, dinv, N);
    scan_kernel<<<1, 1024, 0, stream>>>(cnt, row_ptr, N);
    init_cursor_kernel<<<nbN, THREADS, 0, stream>>>(row_ptr, cursor, N);
    fill_self_kernel<<<nbN, THREADS, 0, stream>>>(cursor, src_sorted, N);
    fill_edges_kernel<<<nbE, THREADS, 0, stream>>>(ei, cursor, src_sorted, E);

    // ---- conversions ----
    convert_x_kernel<<<(int)(((long)N * (F / 4) + 255) / 256), THREADS, 0, stream>>>(x, xs, N, F);
    convert_w_kernel<<<(F * D1 + 255) / 256, THREADS, 0, stream>>>(W1, Wt1, F, D1);
    convert_w_kernel<<<(D1 * D2 + 255) / 256, THREADS, 0, stream>>>(W2, Wt2, D1, D2);

    // ---- layer 1: ts1 = dinv .* (xs @ W1'); h1s = split(relu(dinv*sum + b1)) ----
    {
        dim3 grid(Mpad / 128, D1 / 64);
        gemm_bf16_kernel<<<grid, THREADS, 0, stream>>>(xs, Wt1, dinv, ts1, N, 3 * F, D1);
        agg4_kernel<256, true><<<(N + 3) / 4, THREADS, 0, stream>>>(ts1, row_ptr, src_sorted, dinv, b1, nullptr, h1s, N);
    }
    // ---- layer 2 ----
    {
        dim3 grid(Mpad / 128, D2 / 64);
        gemm_bf16_kernel<<<grid, THREADS, 0, stream>>>(h1s, Wt2, dinv, ts2, N, 3 * D1, D2);
        agg4_kernel<128, false><<<(N + 7) / 8, THREADS, 0, stream>>>(ts2, row_ptr, src_sorted, dinv, b2, h2, nullptr, N);
    }
    // ---- layer 3: 128 -> 32 ----
    {
        int mb = (N + 63) / 64;
        gemm_small_kernel<128, 32><<<mb, THREADS, 0, stream>>>(h2, W3, dinv, ts3, N);
        agg4_kernel<32, false><<<(N + 31) / 32, THREADS, 0, stream>>>(ts3, row_ptr, src_sorted, dinv, b3, h3, nullptr, N);
    }
    // ---- layer K: 32 -> 8 ----
    {
        int mb = (N + 63) / 64;
        gemm_small_kernel<32, 8><<<mb, THREADS, 0, stream>>>(h3, Wk, dinv, tsk, N);
        agg4_kernel<8, false><<<(N + 127) / 128, THREADS, 0, stream>>>(tsk, row_ptr, src_sorted, dinv, bk, z, nullptr, N);
    }
    // ---- decoder ----
    decoder_kernel<<<nbE, THREADS, 0, stream>>>(z, ei, out, E, K);
}

// Round 5
// 521.566 us; speedup vs baseline: 1.7738x; 1.0912x over previous
//
#include <hip/hip_runtime.h>
#include <hip/hip_bf16.h>

#define THREADS 256

typedef __attribute__((ext_vector_type(4))) float f32x4;
typedef __attribute__((ext_vector_type(8))) short short8;
typedef __attribute__((ext_vector_type(4))) unsigned short u16x4;

__device__ inline unsigned short f2bf(float f) {
    unsigned int u = __builtin_bit_cast(unsigned int, f);
    unsigned int r = (u + 0x7FFFu + ((u >> 16) & 1u)) >> 16;
    return (unsigned short)r;
}
__device__ inline float bf2f(unsigned short h) {
    unsigned int u = ((unsigned int)h) << 16;
    return __builtin_bit_cast(float, u);
}

#if defined(__has_builtin)
#if __has_builtin(__builtin_amdgcn_global_load_lds)
#define HAVE_GLOAD_LDS 1
#endif
#endif

// One 16B chunk per lane; lds base must be wave-uniform (HW: base + lane*16).
__device__ __forceinline__ void async_copy16(const void* g, void* lds) {
#ifdef HAVE_GLOAD_LDS
    __builtin_amdgcn_global_load_lds((const __attribute__((address_space(1))) void*)g,
                                     (__attribute__((address_space(3))) void*)lds, 16, 0, 0);
#else
    int lane = threadIdx.x & 63;
    *(short8*)((short*)lds + lane * 8) = *(const short8*)g;
#endif
}

// ---------------- graph preprocessing ----------------

__global__ __launch_bounds__(256) void init_cnt_kernel(int* cnt, int n) {
    int i = blockIdx.x * blockDim.x + threadIdx.x;
    if (i < n) cnt[i] = 1;   // self loop
}

__global__ __launch_bounds__(256) void count_edges_kernel(const int* ei, int* cnt, int E) {
    int e = blockIdx.x * blockDim.x + threadIdx.x;
    if (e < E) atomicAdd(&cnt[ei[E + e]], 1);   // dst row
}

// single-block exclusive scan: 1024 threads, chunked
__global__ __launch_bounds__(1024) void scan_kernel(const int* cnt, int* row_ptr, int n) {
    __shared__ int sh[1024];
    int chunk = (n + 1023) >> 10;
    int beg = (int)threadIdx.x * chunk;
    int end = min(beg + chunk, n);
    int s = 0;
    for (int i = beg; i < end; ++i) s += cnt[i];
    sh[threadIdx.x] = s;
    __syncthreads();
    for (int off = 1; off < 1024; off <<= 1) {
        int t = (threadIdx.x >= (unsigned)off) ? sh[threadIdx.x - off] : 0;
        __syncthreads();
        sh[threadIdx.x] += t;
        __syncthreads();
    }
    int run = sh[threadIdx.x] - s;   // exclusive prefix
    for (int i = beg; i < end; ++i) { row_ptr[i] = run; run += cnt[i]; }
    if (threadIdx.x == 1023) row_ptr[n] = run;
}

// dinv + self-fill + cursor init in one pass
__global__ __launch_bounds__(256) void prep_fused_kernel(const int* cnt, const int* row_ptr,
                                                         int* cursor, float* dinv,
                                                         int* src_sorted, int n) {
    int i = blockIdx.x * blockDim.x + threadIdx.x;
    if (i < n) {
        dinv[i] = rsqrtf((float)cnt[i]);
        int p = row_ptr[i];
        src_sorted[p] = i;     // self loop first (deterministic slot)
        cursor[i] = p + 1;
    }
}

__global__ __launch_bounds__(256) void fill_edges_kernel(const int* ei, int* cursor, int* src_sorted, int E) {
    int e = blockIdx.x * blockDim.x + threadIdx.x;
    if (e < E) {
        int s = ei[e];
        int d = ei[E + e];
        int pos = atomicAdd(&cursor[d], 1);
        src_sorted[pos] = s;
    }
}

// ---------------- split-bf16 conversion ----------------
// x -> [hi | lo]  (row length 2F)
__global__ __launch_bounds__(256) void convert_x_kernel(const float* __restrict__ x,
                                                        unsigned short* __restrict__ xs,
                                                        int n, int F) {
    long idx = (long)blockIdx.x * 256 + threadIdx.x;
    long total = (long)n * (F / 4);
    if (idx >= total) return;
    int row = (int)(idx / (F / 4));
    int c4 = (int)(idx % (F / 4)) * 4;
    f32x4 v = *(const f32x4*)&x[(long)row * F + c4];
    u16x4 hi, lo;
#pragma unroll
    for (int j = 0; j < 4; ++j) {
        hi[j] = f2bf(v[j]);
        lo[j] = f2bf(v[j] - bf2f(hi[j]));
    }
    unsigned short* base = xs + (long)row * 2 * F;
    *(u16x4*)&base[c4] = hi;
    *(u16x4*)&base[F + c4] = lo;
}

// W [K,N] f32 -> Wt [N, 3K] bf16 transposed: rows of B' = [hi; hi; lo]
__global__ __launch_bounds__(256) void convert_w_kernel(const float* __restrict__ W,
                                                        unsigned short* __restrict__ Wt,
                                                        int K, int N) {
    int idx = blockIdx.x * 256 + threadIdx.x;
    if (idx >= K * N) return;
    int k = idx / N, n = idx % N;
    float v = W[(long)k * N + n];
    unsigned short hi = f2bf(v);
    unsigned short lo = f2bf(v - bf2f(hi));
    unsigned short* base = Wt + (long)n * 3 * K;
    base[k] = hi;
    base[K + k] = hi;
    base[2 * K + k] = lo;
}

// ---------------- MFMA bf16 GEMM: C[M,N] = A'[M,Kp] * Bt[N,Kp]^T, epilogue *dinv[row] ----------------
// BM=64, BN=N (one column block, A read exactly once), BK=64, 256 threads = 4 waves.
// A stored [hi|lo] (row len KA=2F); logical third segment [2F,3F) remapped to hi.
// LDS fragment-chunk layout -> conflict-free b128, global_load_lds 16B staging.
template <int BN>
__global__ __launch_bounds__(256) void gemm_bf16_kernel(const unsigned short* __restrict__ A,
                                                        const unsigned short* __restrict__ Bt,
                                                        const float* __restrict__ dinv,
                                                        float* __restrict__ C,
                                                        int M, int KA, int Kp, int N) {
    constexpr int WAVES_N = BN / 64;
    constexpr int WAVES_M = 4 / WAVES_N;
    constexpr int MI = 4 / WAVES_M;       // 16-row tiles per wave (BM=64)
    constexpr int AITERS = 2;             // 512 A-chunks / 256 threads
    constexpr int BITERS = BN / 32;       // (BN/16)*2*64 / 256
    __shared__ short As[64 * 64];
    __shared__ short Bs[BN * 64];
    const int tid = threadIdx.x;
    const int m0 = blockIdx.x * 64;
    const int wave = tid >> 6, l = tid & 63;
    const int wn = wave / WAVES_M, wm = wave % WAVES_M;
    const int lr = l & 15, lg = l >> 4;
    f32x4 acc[MI][4] = {};
    for (int k0 = 0; k0 < Kp; k0 += 64) {
#pragma unroll
        for (int it = 0; it < AITERS; ++it) {
            int chunk = it * 256 + tid;
            int mi = chunk >> 7, ks = (chunk >> 6) & 1, cl = chunk & 63;
            long row = m0 + mi * 16 + (cl & 15);
            int gk = k0 + ks * 32 + ((cl >> 4) << 3);
            if (gk >= KA) gk -= KA;       // [hi|lo|hi] logical from [hi|lo] storage
            async_copy16(&A[row * KA + gk], &As[(size_t)(it * 256 + (tid & ~63)) * 8]);
        }
#pragma unroll
        for (int it = 0; it < BITERS; ++it) {
            int chunk = it * 256 + tid;
            int ni = chunk >> 7, ks = (chunk >> 6) & 1, cl = chunk & 63;
            long col = ni * 16 + (cl & 15);
            int gk = k0 + ks * 32 + ((cl >> 4) << 3);
            async_copy16(&Bt[col * Kp + gk], &Bs[(size_t)(it * 256 + (tid & ~63)) * 8]);
        }
        __syncthreads();
#pragma unroll
        for (int ks = 0; ks < 2; ++ks) {
            short8 a[MI], b[4];
#pragma unroll
            for (int i = 0; i < MI; ++i)
                a[i] = *(const short8*)&As[(((wm * MI + i) * 2 + ks) * 64 + l) * 8];
#pragma unroll
            for (int ni = 0; ni < 4; ++ni)
                b[ni] = *(const short8*)&Bs[(((wn * 4 + ni) * 2 + ks) * 64 + l) * 8];
#pragma unroll
            for (int i = 0; i < MI; ++i)
#pragma unroll
                for (int ni = 0; ni < 4; ++ni)
                    acc[i][ni] = __builtin_amdgcn_mfma_f32_16x16x32_bf16(a[i], b[ni], acc[i][ni], 0, 0, 0);
        }
        __syncthreads();
    }
#pragma unroll
    for (int i = 0; i < MI; ++i) {
        int rbase = m0 + (wm * MI + i) * 16 + lg * 4;
#pragma unroll
        for (int ni = 0; ni < 4; ++ni) {
            int col = wn * 64 + ni * 16 + lr;
#pragma unroll
            for (int r = 0; r < 4; ++r) {
                int row = rbase + r;
                if (row < M) C[(long)row * N + col] = acc[i][ni][r] * dinv[row];
            }
        }
    }
}

// ---------------- aggregation core: 8-deep gather unroll ----------------
template <int G>
__device__ __forceinline__ f32x4 gather_sum(const f32x4* __restrict__ tsv,
                                            const int* __restrict__ src,
                                            int beg, int end, int lane) {
    f32x4 acc = {0.f, 0.f, 0.f, 0.f};
    int e = beg;
    for (; e + 8 <= end; e += 8) {
        int s0 = src[e], s1 = src[e + 1], s2 = src[e + 2], s3 = src[e + 3];
        int s4 = src[e + 4], s5 = src[e + 5], s6 = src[e + 6], s7 = src[e + 7];
        f32x4 v0 = tsv[(long)s0 * G + lane], v1 = tsv[(long)s1 * G + lane];
        f32x4 v2 = tsv[(long)s2 * G + lane], v3 = tsv[(long)s3 * G + lane];
        f32x4 v4 = tsv[(long)s4 * G + lane], v5 = tsv[(long)s5 * G + lane];
        f32x4 v6 = tsv[(long)s6 * G + lane], v7 = tsv[(long)s7 * G + lane];
        acc += ((v0 + v1) + (v2 + v3)) + ((v4 + v5) + (v6 + v7));
    }
    for (; e + 2 <= end; e += 2) {
        int s0 = src[e], s1 = src[e + 1];
        acc += tsv[(long)s0 * G + lane] + tsv[(long)s1 * G + lane];
    }
    if (e < end) acc += tsv[(long)src[e] * G + lane];
    return acc;
}

// D=256: h1 = relu(dinv*sum + b1) -> split bf16 [hi|lo] write (row len 512)
__global__ __launch_bounds__(256) void agg_split256_kernel(const float* __restrict__ ts,
                                                           const int* __restrict__ row_ptr,
                                                           const int* __restrict__ src_sorted,
                                                           const float* __restrict__ dinv,
                                                           const float* __restrict__ bias,
                                                           unsigned short* __restrict__ out_s,
                                                           int n) {
    int g = threadIdx.x >> 6, lane = threadIdx.x & 63;
    int node = blockIdx.x * 4 + g;
    if (node >= n) return;
    f32x4 acc = gather_sum<64>((const f32x4*)ts, src_sorted, row_ptr[node], row_ptr[node + 1], lane);
    float di = dinv[node];
    f32x4 b4 = *(const f32x4*)&bias[lane * 4];
    f32x4 v = acc * di + b4;
    u16x4 hi, lo;
#pragma unroll
    for (int j = 0; j < 4; ++j) {
        float r = fmaxf(v[j], 0.f);
        hi[j] = f2bf(r);
        lo[j] = f2bf(r - bf2f(hi[j]));
    }
    unsigned short* base = out_s + (long)node * 512;
    *(u16x4*)&base[lane * 4] = hi;
    *(u16x4*)&base[256 + lane * 4] = lo;
}

// D=128 agg + fused W3 matvec: ts3[node] = dinv * (relu(dinv*sum+b2) @ W3)   (128 -> 32)
__global__ __launch_bounds__(256) void agg_fused_w3_kernel(const float* __restrict__ ts,
                                                           const int* __restrict__ row_ptr,
                                                           const int* __restrict__ src_sorted,
                                                           const float* __restrict__ dinv,
                                                           const float* __restrict__ bias,
                                                           const float* __restrict__ W3,
                                                           float* __restrict__ ts3, int n) {
    __shared__ float W3s[128 * 32];
    __shared__ float hbuf[8][128];
    for (int i = threadIdx.x; i < 128 * 32; i += 256) W3s[i] = W3[i];
    __syncthreads();
    int g = threadIdx.x >> 5, lane = threadIdx.x & 31;
    int node = blockIdx.x * 8 + g;
    if (node >= n) return;
    f32x4 acc = gather_sum<32>((const f32x4*)ts, src_sorted, row_ptr[node], row_ptr[node + 1], lane);
    float di = dinv[node];
    f32x4 b4 = *(const f32x4*)&bias[lane * 4];
    f32x4 v = acc * di + b4;
#pragma unroll
    for (int j = 0; j < 4; ++j) v[j] = fmaxf(v[j], 0.f);
    *(f32x4*)&hbuf[g][lane * 4] = v;
    float aj = 0.f;
#pragma unroll
    for (int k = 0; k < 128; k += 4) {
        f32x4 hv = *(const f32x4*)&hbuf[g][k];
        aj += hv[0] * W3s[k * 32 + lane] + hv[1] * W3s[(k + 1) * 32 + lane]
            + hv[2] * W3s[(k + 2) * 32 + lane] + hv[3] * W3s[(k + 3) * 32 + lane];
    }
    ts3[(long)node * 32 + lane] = aj * di;
}

// D=32 agg + fused Wk matvec: tsk[node] = dinv * (relu(dinv*sum+b3) @ Wk)    (32 -> 8)
__global__ __launch_bounds__(256) void agg_fused_wk_kernel(const float* __restrict__ ts,
                                                           const int* __restrict__ row_ptr,
                                                           const int* __restrict__ src_sorted,
                                                           const float* __restrict__ dinv,
                                                           const float* __restrict__ bias,
                                                           const float* __restrict__ Wk,
                                                           float* __restrict__ tsk, int n) {
    __shared__ float Wks[32 * 8];
    __shared__ float hbuf[32][32];
    for (int i = threadIdx.x; i < 32 * 8; i += 256) Wks[i] = Wk[i];
    __syncthreads();
    int g = threadIdx.x >> 3, lane = threadIdx.x & 7;
    int node = blockIdx.x * 32 + g;
    if (node >= n) return;
    f32x4 acc = gather_sum<8>((const f32x4*)ts, src_sorted, row_ptr[node], row_ptr[node + 1], lane);
    float di = dinv[node];
    f32x4 b4 = *(const f32x4*)&bias[lane * 4];
    f32x4 v = acc * di + b4;
#pragma unroll
    for (int j = 0; j < 4; ++j) v[j] = fmaxf(v[j], 0.f);
    *(f32x4*)&hbuf[g][lane * 4] = v;
    float aj = 0.f;
#pragma unroll
    for (int k = 0; k < 32; k += 4) {
        f32x4 hv = *(const f32x4*)&hbuf[g][k];
        aj += hv[0] * Wks[k * 8 + lane] + hv[1] * Wks[(k + 1) * 8 + lane]
            + hv[2] * Wks[(k + 2) * 8 + lane] + hv[3] * Wks[(k + 3) * 8 + lane];
    }
    tsk[(long)node * 8 + lane] = aj * di;
}

// D=8: z = relu(dinv*sum + bk)
__global__ __launch_bounds__(256) void agg_plain8_kernel(const float* __restrict__ ts,
                                                         const int* __restrict__ row_ptr,
                                                         const int* __restrict__ src_sorted,
                                                         const float* __restrict__ dinv,
                                                         const float* __restrict__ bias,
                                                         float* __restrict__ z, int n) {
    int g = threadIdx.x >> 1, lane = threadIdx.x & 1;
    int node = blockIdx.x * 128 + g;
    if (node >= n) return;
    f32x4 acc = gather_sum<2>((const f32x4*)ts, src_sorted, row_ptr[node], row_ptr[node + 1], lane);
    float di = dinv[node];
    f32x4 b4 = *(const f32x4*)&bias[lane * 4];
    f32x4 v = acc * di + b4;
#pragma unroll
    for (int j = 0; j < 4; ++j) v[j] = fmaxf(v[j], 0.f);
    *(f32x4*)&z[(long)node * 8 + lane * 4] = v;
}

// ---------------- decoder: out[k,e] = dot(z[s_e], z[d_e]) (identical across k) ----------------
__global__ __launch_bounds__(256) void decoder_kernel(const float* __restrict__ z,
                                                      const int* __restrict__ ei,
                                                      float* __restrict__ out,
                                                      int E, int K) {
    int e = blockIdx.x * blockDim.x + threadIdx.x;
    if (e >= E) return;
    int s = ei[e];
    int d = ei[E + e];
    const f32x4* zv = (const f32x4*)z;
    f32x4 a0 = zv[(long)s * 2], a1 = zv[(long)s * 2 + 1];
    f32x4 b0 = zv[(long)d * 2], b1 = zv[(long)d * 2 + 1];
    f32x4 p = a0 * b0 + a1 * b1;
    float acc = p[0] + p[1] + p[2] + p[3];
    for (int k = 0; k < K; k++) out[(long)k * E + e] = acc;
}

// ---------------- launch ----------------

extern "C" void kernel_launch(void* const* d_in, const int* in_sizes, int n_in,
                              void* d_out, int out_size, void* d_ws, size_t ws_size,
                              hipStream_t stream) {
    const float* x  = (const float*)d_in[0];
    const int*   ei = (const int*)d_in[1];
    const float* W1 = (const float*)d_in[3];
    const float* b1 = (const float*)d_in[4];
    const float* W2 = (const float*)d_in[5];
    const float* b2 = (const float*)d_in[6];
    const float* W3 = (const float*)d_in[7];
    const float* b3 = (const float*)d_in[8];
    const float* Wk = (const float*)d_in[9];
    const float* bk = (const float*)d_in[10];
    float* out = (float*)d_out;

    const int D1 = in_sizes[4];            // 256
    const int D2 = in_sizes[6];            // 128
    const int F  = in_sizes[3] / D1;       // 256
    const int N  = in_sizes[0] / F;        // 50000
    const int E  = in_sizes[1] / 2;        // 800000
    const int K  = out_size / E;           // 8
    const int M  = E + N;                  // edges incl self loops
    const int Mpad = (N + 127) & ~127;     // 50048 (div by 64 and 128)

    size_t off = 0;
    auto alloc = [&](size_t bytes) -> void* {
        off = (off + 255) & ~(size_t)255;
        void* p = (char*)d_ws + off;
        off += bytes;
        return p;
    };
    int*   cnt        = (int*)alloc((size_t)N * sizeof(int));
    int*   row_ptr    = (int*)alloc((size_t)(N + 1) * sizeof(int));
    int*   cursor     = (int*)alloc((size_t)N * sizeof(int));
    float* dinv       = (float*)alloc((size_t)N * sizeof(float));
    int*   src_sorted = (int*)alloc((size_t)M * sizeof(int));
    unsigned short* region_x = (unsigned short*)alloc((size_t)Mpad * 2 * F * sizeof(short));  // xs -> h1s (51.2MB)
    float* region_t   = (float*)alloc((size_t)Mpad * 256 * sizeof(float));                    // ts1 -> ts2 (51.2MB)
    unsigned short* Wt1 = (unsigned short*)alloc((size_t)D1 * 3 * F * sizeof(short));
    unsigned short* Wt2 = (unsigned short*)alloc((size_t)D2 * 3 * D1 * sizeof(short));
    float* ts3        = (float*)alloc((size_t)Mpad * 32 * sizeof(float));
    float* tsk        = (float*)alloc((size_t)Mpad * 8 * sizeof(float));
    float* z          = (float*)alloc((size_t)Mpad * 8 * sizeof(float));
    (void)ws_size; (void)n_in;

    unsigned short* xs  = region_x;
    unsigned short* h1s = region_x;   // reused after GEMM1 consumed xs
    float* ts1 = region_t;
    float* ts2 = region_t;            // reused (GEMM2 writes while reading h1s)

    int nbN = (N + THREADS - 1) / THREADS;
    int nbE = (E + THREADS - 1) / THREADS;

    // ---- graph prep ----
    init_cnt_kernel<<<nbN, THREADS, 0, stream>>>(cnt, N);
    count_edges_kernel<<<nbE, THREADS, 0, stream>>>(ei, cnt, E);
    scan_kernel<<<1, 1024, 0, stream>>>(cnt, row_ptr, N);
    prep_fused_kernel<<<nbN, THREADS, 0, stream>>>(cnt, row_ptr, cursor, dinv, src_sorted, N);
    fill_edges_kernel<<<nbE, THREADS, 0, stream>>>(ei, cursor, src_sorted, E);

    // ---- conversions ----
    convert_x_kernel<<<(int)(((long)N * (F / 4) + 255) / 256), THREADS, 0, stream>>>(x, xs, N, F);
    convert_w_kernel<<<(F * D1 + 255) / 256, THREADS, 0, stream>>>(W1, Wt1, F, D1);
    convert_w_kernel<<<(D1 * D2 + 255) / 256, THREADS, 0, stream>>>(W2, Wt2, D1, D2);

    // ---- layer 1: ts1 = dinv .* (x @ W1)  [MFMA, N=256 single column block] ----
    gemm_bf16_kernel<256><<<Mpad / 64, THREADS, 0, stream>>>(xs, Wt1, dinv, ts1, N, 2 * F, 3 * F, D1);
    agg_split256_kernel<<<(N + 3) / 4, THREADS, 0, stream>>>(ts1, row_ptr, src_sorted, dinv, b1, h1s, N);

    // ---- layer 2: ts2 = dinv .* (h1 @ W2)  [MFMA, N=128] ----
    gemm_bf16_kernel<128><<<Mpad / 64, THREADS, 0, stream>>>(h1s, Wt2, dinv, ts2, N, 2 * D1, 3 * D1, D2);
    agg_fused_w3_kernel<<<(N + 7) / 8, THREADS, 0, stream>>>(ts2, row_ptr, src_sorted, dinv, b2, W3, ts3, N);

    // ---- layer 3+K fused into agg epilogues ----
    agg_fused_wk_kernel<<<(N + 31) / 32, THREADS, 0, stream>>>(ts3, row_ptr, src_sorted, dinv, b3, Wk, tsk, N);
    agg_plain8_kernel<<<(N + 127) / 128, THREADS, 0, stream>>>(tsk, row_ptr, src_sorted, dinv, bk, z, N);

    // ---- decoder ----
    decoder_kernel<<<nbE, THREADS, 0, stream>>>(z, ei, out, E, K);
}